// Round 20
// baseline (3259.361 us; speedup 1.0000x reference)
//
#include <hip/hip_runtime.h>
#include <stdint.h>

// Farthest point sampling, pointops semantics.
// B=8 batches, n=65536, stride=64 -> m=1024 samples/batch.
//
// Round 20: consolidation. Evidence so far: sc0/XCD-local polling saves
// HBM traffic but zero time (r10 vs r8); the device-domain (sc1) probe is
// what actually completes the handshake (r17 regression when cadenced);
// inline-asm fast-exit polling risks rule-18 register hazards (r19's
// exact-65536 corruption). So: SINGLE agent-scope domain, plain
// __hip_atomic loads/stores only (compiler-managed waits, no asm in the
// loop), with the one structural win from r18 kept: the winner's COORDS
// ride in the slot (3 self-tagged 8B cells), deleting the dependent
// end-of-step q-load from p.
//
// Structure (r15 base): 1-wave WGs (64 thr), 32 WGs/batch, 32 pts/thread
// in LDS float4-transposed, zero barriers in the loop, ballot argmax,
// hoisted LDS coord reloads, rotated output writer.
//
// Slot = 4 u64 (32B): c0=(it|dist_bits|0xFFFF-idx), c1=(it|x|y_lo16),
// c2=(it|z|y_hi16), pad. Each cell self-tagged -> no store-ordering
// needed; 8B cells are single-copy atomic. Parity-double-buffered cell
// sets with monotone tags; round-7 induction: slot s's parity cell for
// step it is overwritten only by publish(it+2) from wave s, which follows
// wave s's poll(it+1), which requires EVERY wave published (it+1), which
// each does only after completing poll(it) in wave program order => no
// reader of (it) sees the (it+2) overwrite, no deadlock. Coords are exact
// bit copies of p's floats -> bit-exact FPS chain (ties broken to
// smallest idx at every level). comm memset every launch.

#define G      32    // workgroups (waves) per batch == slots per batch
#define BS     64    // threads per workgroup = 1 wave
#define PPT    32    // points per thread (G*BS*PPT == n)
#define NC     8     // float4 chunks per thread
#define NBATCH 8

typedef unsigned long long u64;
typedef unsigned int u32;

__device__ inline u64 ld_ag(const u64* a) {
    return __hip_atomic_load(a, __ATOMIC_RELAXED, __HIP_MEMORY_SCOPE_AGENT);
}
__device__ inline void st_ag(u64* a, u64 v) {
    __hip_atomic_store(a, v, __ATOMIC_RELAXED, __HIP_MEMORY_SCOPE_AGENT);
}

__global__ __launch_bounds__(BS, 1)
void fps_r20(const float* __restrict__ p, int n, int m,
             u64* __restrict__ comm,
             float* __restrict__ out_np, float* __restrict__ out_no,
             float* __restrict__ out_idx)
{
#pragma clang fp contract(off)
    const int bg   = blockIdx.x;
    const int b    = bg & (NBATCH - 1);
    const int g    = bg >> 3;            // 0..31 within batch
    const int t    = threadIdx.x;        // == lane
    const int gbase = b * n;
    const int tbase = g * (BS * PPT) + t * PPT;  // batch-local thread base

    __shared__ float4 xs[NC * BS], ys[NC * BS], zs[NC * BS];  // 24 KB

    // ---- stage 32 pts/thread into LDS, float4-transposed (one-time) ----
    {
        const float4* pb = (const float4*)(p + 3ull * (u32)(gbase + tbase));
#pragma unroll
        for (int h = 0; h < 2; ++h) {
            float c[48];
#pragma unroll
            for (int v = 0; v < 12; ++v) {
                float4 f = pb[h * 12 + v];
                c[4 * v + 0] = f.x; c[4 * v + 1] = f.y;
                c[4 * v + 2] = f.z; c[4 * v + 3] = f.w;
            }
#pragma unroll
            for (int cc = 0; cc < 4; ++cc) {
                int ch = h * 4 + cc;
                xs[ch * BS + t] = make_float4(c[(cc * 4 + 0) * 3 + 0],
                                              c[(cc * 4 + 1) * 3 + 0],
                                              c[(cc * 4 + 2) * 3 + 0],
                                              c[(cc * 4 + 3) * 3 + 0]);
                ys[ch * BS + t] = make_float4(c[(cc * 4 + 0) * 3 + 1],
                                              c[(cc * 4 + 1) * 3 + 1],
                                              c[(cc * 4 + 2) * 3 + 1],
                                              c[(cc * 4 + 3) * 3 + 1]);
                zs[ch * BS + t] = make_float4(c[(cc * 4 + 0) * 3 + 2],
                                              c[(cc * 4 + 1) * 3 + 2],
                                              c[(cc * 4 + 2) * 3 + 2],
                                              c[(cc * 4 + 3) * 3 + 2]);
            }
        }
    }
    __syncthreads();   // LDS ready; never written again

    float dist[PPT];
#pragma unroll
    for (int j = 0; j < PPT; ++j) dist[j] = 1e10f;

    // coord working set for the upcoming step (hoisted loads)
    float4 CX[NC], CY[NC], CZ[NC];
#pragma unroll
    for (int cc = 0; cc < NC; ++cc) {
        CX[cc] = xs[cc * BS + t];
        CY[cc] = ys[cc * BS + t];
        CZ[cc] = zs[cc * BS + t];
    }

    // first query = point 0 of the batch
    float qx = p[3ull * (u32)gbase + 0];
    float qy = p[3ull * (u32)gbase + 1];
    float qz = p[3ull * (u32)gbase + 2];

    if (g == 0 && t == 0) {
        out_idx[(size_t)b * m] = (float)gbase;
        out_np[(size_t)(b * m) * 3 + 0] = qx;
        out_np[(size_t)(b * m) * 3 + 1] = qy;
        out_np[(size_t)(b * m) * 3 + 2] = qz;
        out_no[b] = (float)((b + 1) * m);
    }

    // per-batch comm (2 KB = 256 u64): parity block = 32 slots x 4 u64
    u64* cb = comm + (size_t)b * 256;

    for (int it = 1; it < m; ++it) {
        // ---- distance update + per-thread argmax, tracking winner coords ----
        float best = -1.0f;
        int   bj   = 0;
        float bx = 0.f, by = 0.f, bz = 0.f;
#pragma unroll
        for (int cc = 0; cc < NC; ++cc) {
            float xl[4] = {CX[cc].x, CX[cc].y, CX[cc].z, CX[cc].w};
            float yl[4] = {CY[cc].x, CY[cc].y, CY[cc].z, CY[cc].w};
            float zl[4] = {CZ[cc].x, CZ[cc].y, CZ[cc].z, CZ[cc].w};
#pragma unroll
            for (int e = 0; e < 4; ++e) {
                float dx = xl[e] - qx;
                float dy = yl[e] - qy;
                float dz = zl[e] - qz;
                float d  = dx * dx + dy * dy + dz * dz;  // contract off
                int j = cc * 4 + e;
                float nd = fminf(dist[j], d);
                dist[j] = nd;
                if (nd > best) {                          // strict >: earliest j
                    best = nd; bj = j;
                    bx = xl[e]; by = yl[e]; bz = zl[e];
                }
            }
        }
        int bidx = tbase + bj;   // batch-local winner idx (ascends with lane)

        // ---- ballot wave argmax: max butterfly + first-max lane pick ----
        float v = best;
#pragma unroll
        for (int off = 1; off < 64; off <<= 1)
            v = fmaxf(v, __shfl_xor(v, off));
        u64 msk = __ballot(best == v);
        int src = __ffsll((unsigned long long)msk) - 1;
        int widx = __shfl(bidx, src);                  // smallest idx among maxima
        u32 pxb = __shfl(__float_as_uint(bx), src);    // winner coords (bits)
        u32 pyb = __shfl(__float_as_uint(by), src);
        u32 pzb = __shfl(__float_as_uint(bz), src);

        const int par = it & 1;
        u64* sb = cb + (size_t)par * 128;    // this parity's 32 slots

        // ---- lane 0: publish 3 self-tagged cells (single domain) ----
        if (t == 0) {
            u64 c0 = ((u64)(u32)it << 48)
                   | ((u64)(u32)__float_as_uint(v) << 16)
                   | (u64)(u32)(0xFFFF - widx);
            u64 c1 = ((u64)(u32)it << 48) | ((u64)pxb << 16) | (u64)(pyb & 0xFFFFu);
            u64 c2 = ((u64)(u32)it << 48) | ((u64)pzb << 16) | (u64)(pyb >> 16);
            u64* sl = sb + (size_t)g * 4;
            st_ag(sl + 0, c0);
            st_ag(sl + 1, c1);
            st_ag(sl + 2, c2);
        }

        // ---- hoisted coord loads for step it+1 (complete under the poll) ----
#pragma unroll
        for (int cc = 0; cc < NC; ++cc) {
            CX[cc] = xs[cc * BS + t];
            CY[cc] = ys[cc * BS + t];
            CZ[cc] = zs[cc * BS + t];
        }

        // ---- poll: lane i watches slot i's 3 cells (all tags must == it) ----
        u64 c0 = 0, c1 = 0, c2 = 0;
        bool ok;
        do {
            ok = true;
            if (t < G) {
                const u64* sl = sb + (size_t)t * 4;
                c0 = ld_ag(sl + 0);
                c1 = ld_ag(sl + 1);
                c2 = ld_ag(sl + 2);
                ok = ((u32)(c0 >> 48) == (u32)it) &&
                     ((u32)(c1 >> 48) == (u32)it) &&
                     ((u32)(c2 >> 48) == (u32)it);
            }
        } while (!__all(ok));

        // ---- key-max butterfly over 64 lanes (upper 32 carry 0) ----
        u64 kmax = (t < G) ? c0 : 0;
#pragma unroll
        for (int off = 1; off < 64; off <<= 1) {
            u64 k2 = __shfl_xor(kmax, off);
            if (k2 > kmax) kmax = k2;
        }
        int kidx = 0xFFFF - (int)(kmax & 0xFFFF);

        // winner coords from the winning lane (exact bit copies of p[])
        u64 wmask = __ballot(t < G && c0 == kmax);
        int wl = __ffsll((unsigned long long)wmask) - 1;
        u32 wx = (u32)((c1 >> 16) & 0xFFFFFFFFu);
        u32 wy = (((u32)(c2 & 0xFFFFu)) << 16) | (u32)(c1 & 0xFFFFu);
        u32 wz = (u32)((c2 >> 16) & 0xFFFFFFFFu);
        qx = __uint_as_float(__shfl(wx, wl));
        qy = __uint_as_float(__shfl(wy, wl));
        qz = __uint_as_float(__shfl(wz, wl));

        // rotated writer: no fixed straggler wave
        if (g == (it & (G - 1)) && t == 0) {
            out_idx[(size_t)b * m + it] = (float)(gbase + kidx);
            out_np[(size_t)(b * m + it) * 3 + 0] = qx;
            out_np[(size_t)(b * m + it) * 3 + 1] = qy;
            out_np[(size_t)(b * m + it) * 3 + 2] = qz;
        }
    }
}

extern "C" void kernel_launch(void* const* d_in, const int* in_sizes, int n_in,
                              void* d_out, int out_size, void* d_ws, size_t ws_size,
                              hipStream_t stream) {
    const float* p = (const float*)d_in[0];
    int N = in_sizes[0] / 3;           // 524288
    int B = in_sizes[1];               // 8
    int n = N / B;                     // 65536
    int m = (out_size / B - 1) / 4;    // 1024

    float* out_np  = (float*)d_out;
    float* out_no  = out_np + (size_t)B * m * 3;
    float* out_idx = out_no + B;

    u64* comm = (u64*)d_ws;
    // clear all slot cells (both parities) every launch
    hipMemsetAsync(d_ws, 0, (size_t)NBATCH * 256 * sizeof(u64), stream);

    fps_r20<<<NBATCH * G, BS, 0, stream>>>(p, n, m, comm,
                                           out_np, out_no, out_idx);
}

// Round 21
// 2005.795 us; speedup vs baseline: 1.6250x; 1.6250x over previous
//
#include <hip/hip_runtime.h>
#include <stdint.h>

// Farthest point sampling, pointops semantics.
// B=8 batches, n=65536, stride=64 -> m=1024 samples/batch.
//
// Round 21 = round 15 verbatim (the 1996us champion), restored after
// rounds 16-20 all regressed. Structure:
//  - 1-wave WGs (64 thr), 32 WGs/batch; 32 pts/thread in LDS
//    float4-transposed; zero barriers in the main loop.
//  - ballot wave argmax (fmax butterfly + __ballot + __ffsll; smallest
//    index wins ties at every level = numpy argmax first-max).
//  - per step, lane 0 dual-publishes a self-contained packed key
//    (it|dist_bits|0xFFFF-idx) to an sc0 cell (XCD-L2 domain; batch =
//    blockIdx%8 is co-XCD under the CP's round-robin) AND an sc1 cell
//    (device domain, guaranteed).
//  - all lanes poll: sc0 probe every iteration, sc1 fallback probe on
//    the SAME iteration when sc0 misses (guaranteed progress: the r14
//    regression was a missing "memory" clobber letting the sc0 load
//    hoist; the r17 regression was cadencing the sc1 probe).
//  - u64 key-max butterfly (upper 32 lanes carry 0); winner coords
//    re-loaded from read-only p (L2-warm; loop has no cache-inv ops).
//  - hoisted LDS coord reloads complete under the poll; output writer
//    rotates across waves (no fixed straggler).
//
// Correctness: keys are 8B single-copy-atomic and self-contained;
// parity-double-buffered cells with monotone tags; round-7 induction:
// slot s's parity cell for step it is overwritten only by publish(it+2)
// from wave s, which follows wave s's poll(it+1), which requires EVERY
// wave published (it+1), which each does only after completing poll(it)
// in wave program order. Both domain copies carry identical payloads;
// stale tags lose the u64 max automatically. comm memset every launch
// -> graph-replay deterministic. Math is bit-exact vs numpy: contract
// off (left-assoc dx*dx+dy*dy+dz*dz), fminf min-dist, first-max argmax.

#define G      32    // workgroups (waves) per batch == slots per batch
#define BS     64    // threads per workgroup = 1 wave
#define PPT    32    // points per thread (G*BS*PPT == n)
#define NC     8     // float4 chunks per thread
#define NBATCH 8

typedef unsigned long long u64;
typedef unsigned int u32;

// key layout: [63:48]=it  [47:16]=float bits of best dist (nonneg)
//             [15:0]=0xFFFF-idx  (bigger wins => smaller idx wins ties,
//             numpy argmax first-max semantics; nonneg IEEE floats
//             compare like their bit patterns)

__device__ inline u64 ld_sc0(const u64* a) {
    u64 v;
    asm volatile("global_load_dwordx2 %0, %1, off sc0\n\t"
                 "s_waitcnt vmcnt(0)"
                 : "=v"(v) : "v"(a) : "memory");
    return v;
}
__device__ inline void st_sc0(u64* a, u64 v) {
    asm volatile("global_store_dwordx2 %0, %1, off sc0"
                 :: "v"(a), "v"(v) : "memory");
}

__global__ __launch_bounds__(BS, 1)
void fps_r21(const float* __restrict__ p, int n, int m,
             u64* __restrict__ comm,
             float* __restrict__ out_np, float* __restrict__ out_no,
             float* __restrict__ out_idx)
{
#pragma clang fp contract(off)
    const int bg   = blockIdx.x;
    const int b    = bg & (NBATCH - 1);  // %8: co-XCD under round-robin CP
    const int g    = bg >> 3;            // 0..31 within batch
    const int t    = threadIdx.x;        // == lane
    const int gbase = b * n;
    const int tbase = g * (BS * PPT) + t * PPT;  // batch-local thread base

    __shared__ float4 xs[NC * BS], ys[NC * BS], zs[NC * BS];  // 24 KB

    // ---- stage 32 pts/thread into LDS, float4-transposed (one-time) ----
    {
        const float4* pb = (const float4*)(p + 3ull * (u32)(gbase + tbase));
#pragma unroll
        for (int h = 0; h < 2; ++h) {
            float c[48];
#pragma unroll
            for (int v = 0; v < 12; ++v) {
                float4 f = pb[h * 12 + v];
                c[4 * v + 0] = f.x; c[4 * v + 1] = f.y;
                c[4 * v + 2] = f.z; c[4 * v + 3] = f.w;
            }
#pragma unroll
            for (int cc = 0; cc < 4; ++cc) {
                int ch = h * 4 + cc;
                xs[ch * BS + t] = make_float4(c[(cc * 4 + 0) * 3 + 0],
                                              c[(cc * 4 + 1) * 3 + 0],
                                              c[(cc * 4 + 2) * 3 + 0],
                                              c[(cc * 4 + 3) * 3 + 0]);
                ys[ch * BS + t] = make_float4(c[(cc * 4 + 0) * 3 + 1],
                                              c[(cc * 4 + 1) * 3 + 1],
                                              c[(cc * 4 + 2) * 3 + 1],
                                              c[(cc * 4 + 3) * 3 + 1]);
                zs[ch * BS + t] = make_float4(c[(cc * 4 + 0) * 3 + 2],
                                              c[(cc * 4 + 1) * 3 + 2],
                                              c[(cc * 4 + 2) * 3 + 2],
                                              c[(cc * 4 + 3) * 3 + 2]);
            }
        }
    }
    __syncthreads();   // LDS ready; never written again

    float dist[PPT];
#pragma unroll
    for (int j = 0; j < PPT; ++j) dist[j] = 1e10f;

    // coord working set for the upcoming step (hoisted loads)
    float4 CX[NC], CY[NC], CZ[NC];
#pragma unroll
    for (int cc = 0; cc < NC; ++cc) {
        CX[cc] = xs[cc * BS + t];
        CY[cc] = ys[cc * BS + t];
        CZ[cc] = zs[cc * BS + t];
    }

    // first query = point 0 of the batch
    float qx = p[3ull * (u32)gbase + 0];
    float qy = p[3ull * (u32)gbase + 1];
    float qz = p[3ull * (u32)gbase + 2];

    if (g == 0 && t == 0) {
        out_idx[(size_t)b * m] = (float)gbase;
        out_np[(size_t)(b * m) * 3 + 0] = qx;
        out_np[(size_t)(b * m) * 3 + 1] = qy;
        out_np[(size_t)(b * m) * 3 + 2] = qz;
        out_no[b] = (float)((b + 1) * m);
    }

    // per-batch comm (1 KB): sc0 cells [par*32], sc1 cells [64 + par*32]
    u64* cb = comm + (size_t)b * 128;

    for (int it = 1; it < m; ++it) {
        // ---- local distance update + per-thread argmax (ids ascend in j) ----
        float best = -1.0f;
        int   bj   = 0;
#pragma unroll
        for (int cc = 0; cc < NC; ++cc) {
            float xl[4] = {CX[cc].x, CX[cc].y, CX[cc].z, CX[cc].w};
            float yl[4] = {CY[cc].x, CY[cc].y, CY[cc].z, CY[cc].w};
            float zl[4] = {CZ[cc].x, CZ[cc].y, CZ[cc].z, CZ[cc].w};
#pragma unroll
            for (int e = 0; e < 4; ++e) {
                float dx = xl[e] - qx;
                float dy = yl[e] - qy;
                float dz = zl[e] - qz;
                float d  = dx * dx + dy * dy + dz * dz;  // contract off
                int j = cc * 4 + e;
                float nd = fminf(dist[j], d);
                dist[j] = nd;
                if (nd > best) { best = nd; bj = j; }    // strict >: earliest j
            }
        }
        int bidx = tbase + bj;   // batch-local winner idx (ascends with lane)

        // ---- ballot wave argmax: max butterfly + first-max lane pick ----
        float v = best;
#pragma unroll
        for (int off = 1; off < 64; off <<= 1)
            v = fmaxf(v, __shfl_xor(v, off));
        u64 msk = __ballot(best == v);
        int src = __ffsll((unsigned long long)msk) - 1;
        int widx = __shfl(bidx, src);    // smallest idx among maxima

        u64* sb0 = cb + (size_t)(it & 1) * G;          // sc0 cells (2 lines)
        u64* sb1 = cb + 2 * G + (size_t)(it & 1) * G;  // sc1 mirrors

        // ---- lane 0: dual publish of this wave's self-contained key ----
        if (t == 0) {
            u64 kk = ((u64)(u32)it << 48)
                   | ((u64)(u32)__float_as_uint(v) << 16)
                   | (u64)(u32)(0xFFFF - widx);
            st_sc0(sb0 + g, kk);
            __hip_atomic_store(sb1 + g, kk, __ATOMIC_RELAXED,
                               __HIP_MEMORY_SCOPE_AGENT);
        }

        // ---- hoisted coord loads for step it+1: lgkm latency completes
        //      under the vm-poll below ("memory"-clobbered asm pins them) ----
#pragma unroll
        for (int cc = 0; cc < NC; ++cc) {
            CX[cc] = xs[cc * BS + t];
            CY[cc] = ys[cc * BS + t];
            CZ[cc] = zs[cc * BS + t];
        }

        // ---- all lanes: dual-probe poll (sc0 fast, sc1 same-iteration
        //      fallback => guaranteed progress) ----
        u64 k = 0;
        bool ok;
        do {
            ok = true;
            if (t < G) {
                k = ld_sc0(sb0 + t);
                if ((u32)(k >> 48) != (u32)it) {
                    k = __hip_atomic_load(sb1 + t, __ATOMIC_RELAXED,
                                          __HIP_MEMORY_SCOPE_AGENT);
                }
                ok = ((u32)(k >> 48) == (u32)it);
            } else {
                k = 0;   // upper lanes: never win the key-max
            }
        } while (!__all(ok));

        // ---- key-max butterfly over 64 lanes (upper 32 carry 0) ----
#pragma unroll
        for (int off = 1; off < 64; off <<= 1) {
            u64 k2 = __shfl_xor(k, off);
            if (k2 > k) k = k2;
        }
        int kidx = 0xFFFF - (int)(k & 0xFFFF);

        // winner coords from read-only p (L2-warm; no cache-inv in loop)
        const float* wp = p + 3ull * (u32)(gbase + kidx);
        qx = wp[0]; qy = wp[1]; qz = wp[2];

        // rotated writer: no fixed straggler wave
        if (g == (it & (G - 1)) && t == 0) {
            out_idx[(size_t)b * m + it] = (float)(gbase + kidx);
            out_np[(size_t)(b * m + it) * 3 + 0] = qx;
            out_np[(size_t)(b * m + it) * 3 + 1] = qy;
            out_np[(size_t)(b * m + it) * 3 + 2] = qz;
        }
    }
}

extern "C" void kernel_launch(void* const* d_in, const int* in_sizes, int n_in,
                              void* d_out, int out_size, void* d_ws, size_t ws_size,
                              hipStream_t stream) {
    const float* p = (const float*)d_in[0];
    int N = in_sizes[0] / 3;           // 524288
    int B = in_sizes[1];               // 8
    int n = N / B;                     // 65536
    int m = (out_size / B - 1) / 4;    // 1024

    float* out_np  = (float*)d_out;
    float* out_no  = out_np + (size_t)B * m * 3;
    float* out_idx = out_no + B;

    u64* comm = (u64*)d_ws;
    // clear all slot cells (both domains, both parities) every launch
    hipMemsetAsync(d_ws, 0, (size_t)NBATCH * 128 * sizeof(u64), stream);

    fps_r21<<<NBATCH * G, BS, 0, stream>>>(p, n, m, comm,
                                           out_np, out_no, out_idx);
}